// Round 3
// baseline (204.962 us; speedup 1.0000x reference)
//
#include <hip/hip_runtime.h>
#include <hip/hip_bf16.h>

#define BSZ   4
#define NTOK  1024
#define DIN   384
#define DST   16
#define MROWS (BSZ * NTOK)     // 4096
#define NCOLS 800              // 384 dts + 384 dtd + 16 B + 16 C
#define KDIM  384
#define NM    (MROWS * DIN)    // 1572864 elements per plane

__device__ __forceinline__ float softplus_f(float z) {
  return (z > 20.0f) ? z : log1pf(expf(z));
}

__device__ __forceinline__ unsigned short f32_to_bf16(float f) {
  unsigned int u = __float_as_uint(f);
  unsigned int rnd = 0x7fffu + ((u >> 16) & 1u);   // round-to-nearest-even
  return (unsigned short)((u + rnd) >> 16);
}

__device__ __forceinline__ float bf16_lo(unsigned int w) { return __uint_as_float(w << 16); }
__device__ __forceinline__ float bf16_hi(unsigned int w) { return __uint_as_float(w & 0xffff0000u); }

// ---------------------------------------------------------------------------
// Kernel 1: fused projection GEMM (4096 x 800 x 384).
//   delta cols -> activated, bf16, written TRANSPOSED (d-major planes in d_out)
//   B/C cols   -> f32 to ws (row-major, small)
//   bn==0 blocks also stream xT (d-major f32 copy of x) from the As tiles.
// ---------------------------------------------------------------------------
__global__ __launch_bounds__(256) void proj_kernel(
    const float* __restrict__ x,
    const float* __restrict__ Wdts, const float* __restrict__ bdts,
    const float* __restrict__ Wdtd, const float* __restrict__ bdtd,
    const float* __restrict__ WB,   const float* __restrict__ WC,
    unsigned short* __restrict__ dsT, unsigned short* __restrict__ ddT,
    float* __restrict__ Bmat, float* __restrict__ Cmat,
    float* __restrict__ xT)
{
  __shared__ float smem[2 * 32 * 68];       // As | Bs (17408 B); reused for epilogue staging
  float* Asp = smem;                        // As[k][m] stride 68
  float* Bsp = smem + 32 * 68;              // Bs[k][c] stride 68

  const int t    = threadIdx.x;
  const int bm   = blockIdx.x & 63;
  const int bn   = blockIdx.x >> 6;
  const int row0 = bm * 64, col0 = bn * 64;
  const int bb   = row0 >> 10;              // batch index (64 | 1024 so tiles never straddle)
  const int n0   = row0 & 1023;
  const int tx = t & 15, ty = t >> 4;
  const int lr = t >> 3;                    // 0..31
  const int lk = (t & 7) * 4;               // 0..28

  float acc[4][4] = {{0.f,0.f,0.f,0.f},{0.f,0.f,0.f,0.f},
                     {0.f,0.f,0.f,0.f},{0.f,0.f,0.f,0.f}};

  for (int k0 = 0; k0 < KDIM; k0 += 32) {
#pragma unroll
    for (int h = 0; h < 2; ++h) {
      int r = lr + h * 32;
      float4 v = *(const float4*)&x[(long)(row0 + r) * KDIM + k0 + lk];
      Asp[(lk+0)*68 + r] = v.x; Asp[(lk+1)*68 + r] = v.y;
      Asp[(lk+2)*68 + r] = v.z; Asp[(lk+3)*68 + r] = v.w;
    }
#pragma unroll
    for (int h = 0; h < 2; ++h) {
      int cc = lr + h * 32;
      int c  = col0 + cc;
      float4 v = make_float4(0.f, 0.f, 0.f, 0.f);
      if (c < NCOLS) {
        const float* wrow;
        if (c < 384)      wrow = Wdts + (long)c * KDIM;
        else if (c < 768) wrow = Wdtd + (long)(c - 384) * KDIM;
        else if (c < 784) wrow = WB   + (long)(c - 768) * KDIM;
        else              wrow = WC   + (long)(c - 784) * KDIM;
        v = *(const float4*)&wrow[k0 + lk];
      }
      Bsp[(lk+0)*68 + cc] = v.x; Bsp[(lk+1)*68 + cc] = v.y;
      Bsp[(lk+2)*68 + cc] = v.z; Bsp[(lk+3)*68 + cc] = v.w;
    }
    __syncthreads();
#pragma unroll
    for (int k = 0; k < 32; ++k) {
      float4 a   = *(const float4*)&Asp[k*68 + ty*4];
      float4 bb4 = *(const float4*)&Bsp[k*68 + tx*4];
      float av[4] = {a.x, a.y, a.z, a.w};
      float bv[4] = {bb4.x, bb4.y, bb4.z, bb4.w};
#pragma unroll
      for (int i = 0; i < 4; ++i)
#pragma unroll
        for (int jj = 0; jj < 4; ++jj)
          acc[i][jj] = fmaf(av[i], bv[jj], acc[i][jj]);
    }
    // xT streaming: As holds x[row0..row0+63][k0..k0+31] transposed already.
    if (bn == 0) {
      int kk = t >> 3, seg = t & 7, m0 = seg * 8;
      float4 v0 = *(const float4*)&Asp[kk*68 + m0];
      float4 v1 = *(const float4*)&Asp[kk*68 + m0 + 4];
      long o = (long)(bb * DIN + k0 + kk) * NTOK + n0 + m0;
      *(float4*)&xT[o]     = v0;
      *(float4*)&xT[o + 4] = v1;
    }
    __syncthreads();
  }

  if (bn < 12) {
    // delta tile: activate, pack bf16, transpose via LDS, write d-major coalesced
    const float* bias = (bn < 6) ? bdts : bdtd;
    unsigned short* plane = (bn < 6) ? dsT : ddT;
    const int cbase = (bn < 6) ? col0 : col0 - 384;   // d index of local col 0
    unsigned int* st32 = (unsigned int*)smem;         // [64 cols][36] u32 (pairs along n)
#pragma unroll
    for (int jj = 0; jj < 4; ++jj) {
      int cl = tx * 4 + jj;
      float b0 = bias[cbase + cl];
      float v0 = fminf(softplus_f(acc[0][jj] + b0), 0.15f);
      float v1 = fminf(softplus_f(acc[1][jj] + b0), 0.15f);
      float v2 = fminf(softplus_f(acc[2][jj] + b0), 0.15f);
      float v3 = fminf(softplus_f(acc[3][jj] + b0), 0.15f);
      unsigned int w0 = (unsigned int)f32_to_bf16(v0) | ((unsigned int)f32_to_bf16(v1) << 16);
      unsigned int w1 = (unsigned int)f32_to_bf16(v2) | ((unsigned int)f32_to_bf16(v3) << 16);
      st32[cl * 36 + ty * 2 + 0] = w0;
      st32[cl * 36 + ty * 2 + 1] = w1;
    }
    __syncthreads();
    {
      int cl = t >> 2, seg = t & 3;
      uint4 w0 = *(const uint4*)&st32[cl * 36 + seg * 8];
      uint4 w1 = *(const uint4*)&st32[cl * 36 + seg * 8 + 4];
      long addr = (long)(bb * DIN + cbase + cl) * NTOK + n0 + seg * 16;
      *(uint4*)&plane[addr]     = w0;   // 8 bf16 values (n .. n+7)
      *(uint4*)&plane[addr + 8] = w1;   // n+8 .. n+15
    }
  } else {
    // B/C tile: direct f32 writes (small)
#pragma unroll
    for (int i = 0; i < 4; ++i) {
      int r = row0 + ty * 4 + i;
#pragma unroll
      for (int jj = 0; jj < 4; ++jj) {
        int c = col0 + tx * 4 + jj;
        float v = acc[i][jj];
        if (c < 784)       Bmat[(long)r * DST + (c - 768)] = v;
        else if (c < 800)  Cmat[(long)r * DST + (c - 784)] = v;
      }
    }
  }
}

// ---------------------------------------------------------------------------
// Kernel 2: per-(b,d) recurrence. 512 threads x 2 rows. h mirrored bf16 in LDS
// (48 B/row stride: 16-B-aligned b128 reads, low-conflict).
// All global I/O d-major (coalesced).
// ---------------------------------------------------------------------------
__global__ __launch_bounds__(512, 4) void ssm_kernel(
    const float* __restrict__ xT,
    const unsigned short* __restrict__ dsT,
    const unsigned short* __restrict__ ddT,
    const float* __restrict__ Bmat, const float* __restrict__ Cmat,
    const float* __restrict__ Dparam, const float* __restrict__ Alog,
    const float* __restrict__ diffraw, const int* __restrict__ Kp,
    float* __restrict__ yT)
{
  __shared__ unsigned int hl[NTOK * 12];    // 49152 B: 8 u32 data + 4 pad per row
  const int t = threadIdx.x;
  const int d = blockIdx.x % DIN;
  const int b = blockIdx.x / DIN;
  const int K = Kp[0];
  const float dt = 1.0f / (float)K;
  const float Dc = 0.5f / (1.0f + expf(-diffraw[d]));
  const float Dp = Dparam[d];

  float A_s[16];
#pragma unroll
  for (int s = 0; s < 16; ++s)
    A_s[s] = -log1pf(expf(Alog[d * DST + s]));

  const long col = (long)(b * DIN + d) * NTOK;

  float hreg[2][16], h0r[2][16], a1[2], a2[2], resid[2];
#pragma unroll
  for (int j = 0; j < 2; ++j) {
    const int n = t + j * 512;
    float xv = xT[col + n];
    resid[j] = xv * Dp;
    float dsv = __uint_as_float((unsigned int)dsT[col + n] << 16);
    float ddv = __uint_as_float((unsigned int)ddT[col + n] << 16);
    a1[j] = dt * dsv;
    a2[j] = dt * ddv * Dc;
    const float4* Bp = (const float4*)&Bmat[(long)(b * NTOK + n) * DST];
#pragma unroll
    for (int q = 0; q < 4; ++q) {
      float4 bv = Bp[q];
      h0r[j][q*4+0] = xv * bv.x; h0r[j][q*4+1] = xv * bv.y;
      h0r[j][q*4+2] = xv * bv.z; h0r[j][q*4+3] = xv * bv.w;
    }
#pragma unroll
    for (int s = 0; s < 16; ++s) hreg[j][s] = h0r[j][s];
    unsigned int pk[8];
#pragma unroll
    for (int q = 0; q < 8; ++q)
      pk[q] = (__float_as_uint(hreg[j][2*q]) >> 16) |
              (__float_as_uint(hreg[j][2*q+1]) & 0xffff0000u);
    *(uint4*)&hl[n * 12]     = make_uint4(pk[0], pk[1], pk[2], pk[3]);
    *(uint4*)&hl[n * 12 + 4] = make_uint4(pk[4], pk[5], pk[6], pk[7]);
  }
  __syncthreads();

  for (int k = 0; k < K; ++k) {
#pragma unroll
    for (int j = 0; j < 2; ++j) {
      const int n = t + j * 512;
      const int r = n >> 5, c = n & 31;
      const int ou  = ((r > 0)  ? n - 32 : n) * 12;
      const int od  = ((r < 31) ? n + 32 : n) * 12;
      const int ol  = ((c > 0)  ? n - 1  : n) * 12;
      const int orr = ((c < 31) ? n + 1  : n) * 12;
#pragma unroll
      for (int hh = 0; hh < 2; ++hh) {
        uint4 qu = *(const uint4*)&hl[ou  + hh * 4];
        uint4 qd = *(const uint4*)&hl[od  + hh * 4];
        uint4 ql = *(const uint4*)&hl[ol  + hh * 4];
        uint4 qr = *(const uint4*)&hl[orr + hh * 4];
        float lap[8];
#pragma unroll
        for (int w = 0; w < 4; ++w) {
          unsigned int uw = (&qu.x)[w], dw = (&qd.x)[w];
          unsigned int lw = (&ql.x)[w], rw = (&qr.x)[w];
          lap[2*w]   = (bf16_lo(uw) + bf16_lo(dw)) + (bf16_lo(lw) + bf16_lo(rw));
          lap[2*w+1] = (bf16_hi(uw) + bf16_hi(dw)) + (bf16_hi(lw) + bf16_hi(rw));
        }
#pragma unroll
        for (int e = 0; e < 8; ++e) {
          const int s = hh * 8 + e;
          float ce = hreg[j][s];
          float lp = lap[e] - 4.0f * ce;
          float t1 = fmaf(A_s[s], ce, h0r[j][s]);   // A*h + h0
          float hv = fmaf(a1[j], t1, ce);           // h + dt*ds*(...)
          hreg[j][s] = fmaf(a2[j], lp, hv);         // + dt*dd*Dc*lap
        }
      }
    }
    if (k + 1 < K) {
      __syncthreads();
#pragma unroll
      for (int j = 0; j < 2; ++j) {
        const int n = t + j * 512;
        unsigned int pk[8];
#pragma unroll
        for (int q = 0; q < 8; ++q)
          pk[q] = (__float_as_uint(hreg[j][2*q]) >> 16) |
                  (__float_as_uint(hreg[j][2*q+1]) & 0xffff0000u);
        *(uint4*)&hl[n * 12]     = make_uint4(pk[0], pk[1], pk[2], pk[3]);
        *(uint4*)&hl[n * 12 + 4] = make_uint4(pk[4], pk[5], pk[6], pk[7]);
      }
      __syncthreads();
    }
  }

#pragma unroll
  for (int j = 0; j < 2; ++j) {
    const int n = t + j * 512;
    const float4* Cp = (const float4*)&Cmat[(long)(b * NTOK + n) * DST];
    float acc = 0.f;
#pragma unroll
    for (int q = 0; q < 4; ++q) {
      float4 cv = Cp[q];
      acc += hreg[j][q*4+0] * cv.x + hreg[j][q*4+1] * cv.y +
             hreg[j][q*4+2] * cv.z + hreg[j][q*4+3] * cv.w;
    }
    yT[col + n] = acc + resid[j];
  }
}

// ---------------------------------------------------------------------------
// Kernel 3: yT (b,d,n) -> out (b,n,d), both sides coalesced via LDS tile.
// ---------------------------------------------------------------------------
__global__ __launch_bounds__(256) void untranspose_kernel(
    const float* __restrict__ yT, float* __restrict__ out)
{
  __shared__ float tile[32][33];
  const int n0 = blockIdx.x * 32;
  const int d0 = blockIdx.y * 32;
  const int b  = blockIdx.z;
  const int tx = threadIdx.x & 31, ty = threadIdx.x >> 5;   // ty 0..7
#pragma unroll
  for (int i = 0; i < 4; ++i) {
    int dd = d0 + ty + i * 8;
    tile[ty + i * 8][tx] = yT[(long)(b * DIN + dd) * NTOK + n0 + tx];
  }
  __syncthreads();
#pragma unroll
  for (int i = 0; i < 4; ++i) {
    int nn = n0 + ty + i * 8;
    out[(long)(b * NTOK + nn) * DIN + d0 + tx] = tile[tx][ty + i * 8];
  }
}

extern "C" void kernel_launch(void* const* d_in, const int* in_sizes, int n_in,
                              void* d_out, int out_size, void* d_ws, size_t ws_size,
                              hipStream_t stream) {
  const float* x     = (const float*)d_in[0];
  const float* Wdts  = (const float*)d_in[1];
  const float* bdts  = (const float*)d_in[2];
  const float* Wdtd  = (const float*)d_in[3];
  const float* bdtd  = (const float*)d_in[4];
  const float* WB    = (const float*)d_in[5];
  const float* WC    = (const float*)d_in[6];
  const float* Dpar  = (const float*)d_in[7];
  const float* Alog  = (const float*)d_in[8];
  const float* diffr = (const float*)d_in[9];
  const int*   Kst   = (const int*)d_in[10];

  // ws layout (13.1 MB): Bmat | Cmat | xT | yT
  float* Bmat = (float*)d_ws;
  float* Cmat = Bmat + (long)MROWS * DST;
  float* xT   = Cmat + (long)MROWS * DST;
  float* yT   = xT + NM;

  // d_out doubles as scratch for the bf16 delta planes between kernels 1 and 2
  unsigned short* dsT = (unsigned short*)d_out;
  unsigned short* ddT = dsT + NM;

  proj_kernel<<<dim3(64 * 13), dim3(256), 0, stream>>>(
      x, Wdts, bdts, Wdtd, bdtd, WB, WC, dsT, ddT, Bmat, Cmat, xT);

  ssm_kernel<<<dim3(BSZ * DIN), dim3(512), 0, stream>>>(
      xT, dsT, ddT, Bmat, Cmat, Dpar, Alog, diffr, Kst, yT);

  untranspose_kernel<<<dim3(NTOK / 32, DIN / 32, BSZ), dim3(256), 0, stream>>>(
      yT, (float*)d_out);
}

// Round 9
// 142.603 us; speedup vs baseline: 1.4373x; 1.4373x over previous
//
#include <hip/hip_runtime.h>
#include <hip/hip_bf16.h>

#define BSZ   4
#define NTOK  1024
#define DIN   384
#define DST   16
#define MROWS (BSZ * NTOK)     // 4096
#define NCOLS 800              // 384 dts + 384 dtd + 16 B + 16 C
#define KDIM  384
#define NM    (MROWS * DIN)    // 1572864 elements per plane

__device__ __forceinline__ float softplus_f(float z) {
  return (z > 20.0f) ? z : log1pf(expf(z));
}

__device__ __forceinline__ unsigned short f32_to_bf16(float f) {
  unsigned int u = __float_as_uint(f);
  unsigned int rnd = 0x7fffu + ((u >> 16) & 1u);   // round-to-nearest-even
  return (unsigned short)((u + rnd) >> 16);
}

__device__ __forceinline__ float bf16_lo(unsigned int w) { return __uint_as_float(w << 16); }
__device__ __forceinline__ float bf16_hi(unsigned int w) { return __uint_as_float(w & 0xffff0000u); }

// ---------------------------------------------------------------------------
// Kernel 0: x (b,n,d) -> xT (b,d,n). Both sides coalesced via padded LDS tile.
// ---------------------------------------------------------------------------
__global__ __launch_bounds__(256) void xpose_kernel(
    const float* __restrict__ x, float* __restrict__ xT)
{
  __shared__ float tile[32][33];
  const int n0 = blockIdx.x * 32;
  const int d0 = blockIdx.y * 32;
  const int b  = blockIdx.z;
  const int tx = threadIdx.x & 31, ty = threadIdx.x >> 5;   // ty 0..7
#pragma unroll
  for (int i = 0; i < 4; ++i) {
    int nn = n0 + ty + i * 8;
    tile[ty + i * 8][tx] = x[(long)(b * NTOK + nn) * DIN + d0 + tx];
  }
  __syncthreads();
#pragma unroll
  for (int i = 0; i < 4; ++i) {
    int dd = d0 + ty + i * 8;
    xT[(long)(b * DIN + dd) * NTOK + n0 + tx] = tile[tx][ty + i * 8];
  }
}

// ---------------------------------------------------------------------------
// Kernel 1: fused projection GEMM (4096 x 800 x 384).
//   delta cols -> activated, bf16, written TRANSPOSED (d-major planes in d_out)
//   B/C cols   -> f32 to ws (row-major, small)
// ---------------------------------------------------------------------------
__global__ __launch_bounds__(256) void proj_kernel(
    const float* __restrict__ x,
    const float* __restrict__ Wdts, const float* __restrict__ bdts,
    const float* __restrict__ Wdtd, const float* __restrict__ bdtd,
    const float* __restrict__ WB,   const float* __restrict__ WC,
    unsigned short* __restrict__ dsT, unsigned short* __restrict__ ddT,
    float* __restrict__ Bmat, float* __restrict__ Cmat)
{
  __shared__ float smem[2 * 32 * 68];       // As | Bs (17408 B); reused for epilogue staging
  float* Asp = smem;                        // As[k][m] stride 68
  float* Bsp = smem + 32 * 68;              // Bs[k][c] stride 68

  const int t    = threadIdx.x;
  const int bm   = blockIdx.x & 63;
  const int bn   = blockIdx.x >> 6;
  const int row0 = bm * 64, col0 = bn * 64;
  const int bb   = row0 >> 10;              // batch index (64 | 1024 so tiles never straddle)
  const int n0   = row0 & 1023;
  const int tx = t & 15, ty = t >> 4;
  const int lr = t >> 3;                    // 0..31
  const int lk = (t & 7) * 4;               // 0..28

  float acc[4][4] = {{0.f,0.f,0.f,0.f},{0.f,0.f,0.f,0.f},
                     {0.f,0.f,0.f,0.f},{0.f,0.f,0.f,0.f}};

  for (int k0 = 0; k0 < KDIM; k0 += 32) {
#pragma unroll
    for (int h = 0; h < 2; ++h) {
      int r = lr + h * 32;
      float4 v = *(const float4*)&x[(long)(row0 + r) * KDIM + k0 + lk];
      Asp[(lk+0)*68 + r] = v.x; Asp[(lk+1)*68 + r] = v.y;
      Asp[(lk+2)*68 + r] = v.z; Asp[(lk+3)*68 + r] = v.w;
    }
#pragma unroll
    for (int h = 0; h < 2; ++h) {
      int cc = lr + h * 32;
      int c  = col0 + cc;
      float4 v = make_float4(0.f, 0.f, 0.f, 0.f);
      if (c < NCOLS) {
        const float* wrow;
        if (c < 384)      wrow = Wdts + (long)c * KDIM;
        else if (c < 768) wrow = Wdtd + (long)(c - 384) * KDIM;
        else if (c < 784) wrow = WB   + (long)(c - 768) * KDIM;
        else              wrow = WC   + (long)(c - 784) * KDIM;
        v = *(const float4*)&wrow[k0 + lk];
      }
      Bsp[(lk+0)*68 + cc] = v.x; Bsp[(lk+1)*68 + cc] = v.y;
      Bsp[(lk+2)*68 + cc] = v.z; Bsp[(lk+3)*68 + cc] = v.w;
    }
    __syncthreads();
#pragma unroll
    for (int k = 0; k < 32; ++k) {
      float4 a   = *(const float4*)&Asp[k*68 + ty*4];
      float4 bb4 = *(const float4*)&Bsp[k*68 + tx*4];
      float av[4] = {a.x, a.y, a.z, a.w};
      float bv[4] = {bb4.x, bb4.y, bb4.z, bb4.w};
#pragma unroll
      for (int i = 0; i < 4; ++i)
#pragma unroll
        for (int jj = 0; jj < 4; ++jj)
          acc[i][jj] = fmaf(av[i], bv[jj], acc[i][jj]);
    }
    __syncthreads();
  }

  if (bn < 12) {
    // delta tile: activate, pack bf16, transpose via LDS, write d-major coalesced
    const float* bias = (bn < 6) ? bdts : bdtd;
    unsigned short* plane = (bn < 6) ? dsT : ddT;
    const int cbase = (bn < 6) ? col0 : col0 - 384;   // d index of local col 0
    unsigned int* st32 = (unsigned int*)smem;         // [64 cols][36] u32 (pairs along n)
#pragma unroll
    for (int jj = 0; jj < 4; ++jj) {
      int cl = tx * 4 + jj;
      float b0 = bias[cbase + cl];
      float v0 = fminf(softplus_f(acc[0][jj] + b0), 0.15f);
      float v1 = fminf(softplus_f(acc[1][jj] + b0), 0.15f);
      float v2 = fminf(softplus_f(acc[2][jj] + b0), 0.15f);
      float v3 = fminf(softplus_f(acc[3][jj] + b0), 0.15f);
      unsigned int w0 = (unsigned int)f32_to_bf16(v0) | ((unsigned int)f32_to_bf16(v1) << 16);
      unsigned int w1 = (unsigned int)f32_to_bf16(v2) | ((unsigned int)f32_to_bf16(v3) << 16);
      st32[cl * 36 + ty * 2 + 0] = w0;
      st32[cl * 36 + ty * 2 + 1] = w1;
    }
    __syncthreads();
    {
      int cl = t >> 2, seg = t & 3;
      uint4 w0 = *(const uint4*)&st32[cl * 36 + seg * 8];
      uint4 w1 = *(const uint4*)&st32[cl * 36 + seg * 8 + 4];
      long addr = (long)(bb * DIN + cbase + cl) * NTOK + n0 + seg * 16;
      *(uint4*)&plane[addr]     = w0;   // 8 bf16 values (n .. n+7)
      *(uint4*)&plane[addr + 8] = w1;   // n+8 .. n+15
    }
  } else {
    // B/C tile: direct f32 writes (small)
#pragma unroll
    for (int i = 0; i < 4; ++i) {
      int r = row0 + ty * 4 + i;
#pragma unroll
      for (int jj = 0; jj < 4; ++jj) {
        int c = col0 + tx * 4 + jj;
        float v = acc[i][jj];
        if (c < 784)       Bmat[(long)r * DST + (c - 768)] = v;
        else if (c < 800)  Cmat[(long)r * DST + (c - 784)] = v;
      }
    }
  }
}

// ---------------------------------------------------------------------------
// Kernel 2: per-(b,d) recurrence. 512 threads x 2 rows. h mirrored bf16 in LDS
// (48 B/row stride: 16-B-aligned b128 reads, low-conflict).
// All global I/O d-major (coalesced).
// ---------------------------------------------------------------------------
__global__ __launch_bounds__(512, 4) void ssm_kernel(
    const float* __restrict__ xT,
    const unsigned short* __restrict__ dsT,
    const unsigned short* __restrict__ ddT,
    const float* __restrict__ Bmat, const float* __restrict__ Cmat,
    const float* __restrict__ Dparam, const float* __restrict__ Alog,
    const float* __restrict__ diffraw, const int* __restrict__ Kp,
    float* __restrict__ yT)
{
  __shared__ unsigned int hl[NTOK * 12];    // 49152 B: 8 u32 data + 4 pad per row
  const int t = threadIdx.x;
  const int d = blockIdx.x % DIN;
  const int b = blockIdx.x / DIN;
  const int K = Kp[0];
  const float dt = 1.0f / (float)K;
  const float Dc = 0.5f / (1.0f + expf(-diffraw[d]));
  const float Dp = Dparam[d];

  float A_s[16];
#pragma unroll
  for (int s = 0; s < 16; ++s)
    A_s[s] = -log1pf(expf(Alog[d * DST + s]));

  const long col = (long)(b * DIN + d) * NTOK;

  float hreg[2][16], h0r[2][16], a1[2], a2[2], resid[2];
#pragma unroll
  for (int j = 0; j < 2; ++j) {
    const int n = t + j * 512;
    float xv = xT[col + n];
    resid[j] = xv * Dp;
    float dsv = __uint_as_float((unsigned int)dsT[col + n] << 16);
    float ddv = __uint_as_float((unsigned int)ddT[col + n] << 16);
    a1[j] = dt * dsv;
    a2[j] = dt * ddv * Dc;
    const float4* Bp = (const float4*)&Bmat[(long)(b * NTOK + n) * DST];
#pragma unroll
    for (int q = 0; q < 4; ++q) {
      float4 bv = Bp[q];
      h0r[j][q*4+0] = xv * bv.x; h0r[j][q*4+1] = xv * bv.y;
      h0r[j][q*4+2] = xv * bv.z; h0r[j][q*4+3] = xv * bv.w;
    }
#pragma unroll
    for (int s = 0; s < 16; ++s) hreg[j][s] = h0r[j][s];
    unsigned int pk[8];
#pragma unroll
    for (int q = 0; q < 8; ++q)
      pk[q] = (__float_as_uint(hreg[j][2*q]) >> 16) |
              (__float_as_uint(hreg[j][2*q+1]) & 0xffff0000u);
    *(uint4*)&hl[n * 12]     = make_uint4(pk[0], pk[1], pk[2], pk[3]);
    *(uint4*)&hl[n * 12 + 4] = make_uint4(pk[4], pk[5], pk[6], pk[7]);
  }
  __syncthreads();

  for (int k = 0; k < K; ++k) {
#pragma unroll
    for (int j = 0; j < 2; ++j) {
      const int n = t + j * 512;
      const int r = n >> 5, c = n & 31;
      const int ou  = ((r > 0)  ? n - 32 : n) * 12;
      const int od  = ((r < 31) ? n + 32 : n) * 12;
      const int ol  = ((c > 0)  ? n - 1  : n) * 12;
      const int orr = ((c < 31) ? n + 1  : n) * 12;
#pragma unroll
      for (int hh = 0; hh < 2; ++hh) {
        uint4 qu = *(const uint4*)&hl[ou  + hh * 4];
        uint4 qd = *(const uint4*)&hl[od  + hh * 4];
        uint4 ql = *(const uint4*)&hl[ol  + hh * 4];
        uint4 qr = *(const uint4*)&hl[orr + hh * 4];
        float lap[8];
#pragma unroll
        for (int w = 0; w < 4; ++w) {
          unsigned int uw = (&qu.x)[w], dw = (&qd.x)[w];
          unsigned int lw = (&ql.x)[w], rw = (&qr.x)[w];
          lap[2*w]   = (bf16_lo(uw) + bf16_lo(dw)) + (bf16_lo(lw) + bf16_lo(rw));
          lap[2*w+1] = (bf16_hi(uw) + bf16_hi(dw)) + (bf16_hi(lw) + bf16_hi(rw));
        }
#pragma unroll
        for (int e = 0; e < 8; ++e) {
          const int s = hh * 8 + e;
          float ce = hreg[j][s];
          float lp = lap[e] - 4.0f * ce;
          float t1 = fmaf(A_s[s], ce, h0r[j][s]);   // A*h + h0
          float hv = fmaf(a1[j], t1, ce);           // h + dt*ds*(...)
          hreg[j][s] = fmaf(a2[j], lp, hv);         // + dt*dd*Dc*lap
        }
      }
    }
    if (k + 1 < K) {
      __syncthreads();
#pragma unroll
      for (int j = 0; j < 2; ++j) {
        const int n = t + j * 512;
        unsigned int pk[8];
#pragma unroll
        for (int q = 0; q < 8; ++q)
          pk[q] = (__float_as_uint(hreg[j][2*q]) >> 16) |
                  (__float_as_uint(hreg[j][2*q+1]) & 0xffff0000u);
        *(uint4*)&hl[n * 12]     = make_uint4(pk[0], pk[1], pk[2], pk[3]);
        *(uint4*)&hl[n * 12 + 4] = make_uint4(pk[4], pk[5], pk[6], pk[7]);
      }
      __syncthreads();
    }
  }

#pragma unroll
  for (int j = 0; j < 2; ++j) {
    const int n = t + j * 512;
    const float4* Cp = (const float4*)&Cmat[(long)(b * NTOK + n) * DST];
    float acc = 0.f;
#pragma unroll
    for (int q = 0; q < 4; ++q) {
      float4 cv = Cp[q];
      acc += hreg[j][q*4+0] * cv.x + hreg[j][q*4+1] * cv.y +
             hreg[j][q*4+2] * cv.z + hreg[j][q*4+3] * cv.w;
    }
    yT[col + n] = acc + resid[j];
  }
}

// ---------------------------------------------------------------------------
// Kernel 3: yT (b,d,n) -> out (b,n,d), both sides coalesced via LDS tile.
// ---------------------------------------------------------------------------
__global__ __launch_bounds__(256) void untranspose_kernel(
    const float* __restrict__ yT, float* __restrict__ out)
{
  __shared__ float tile[32][33];
  const int n0 = blockIdx.x * 32;
  const int d0 = blockIdx.y * 32;
  const int b  = blockIdx.z;
  const int tx = threadIdx.x & 31, ty = threadIdx.x >> 5;   // ty 0..7
#pragma unroll
  for (int i = 0; i < 4; ++i) {
    int dd = d0 + ty + i * 8;
    tile[ty + i * 8][tx] = yT[(long)(b * DIN + dd) * NTOK + n0 + tx];
  }
  __syncthreads();
#pragma unroll
  for (int i = 0; i < 4; ++i) {
    int nn = n0 + ty + i * 8;
    out[(long)(b * NTOK + nn) * DIN + d0 + tx] = tile[tx][ty + i * 8];
  }
}

extern "C" void kernel_launch(void* const* d_in, const int* in_sizes, int n_in,
                              void* d_out, int out_size, void* d_ws, size_t ws_size,
                              hipStream_t stream) {
  const float* x     = (const float*)d_in[0];
  const float* Wdts  = (const float*)d_in[1];
  const float* bdts  = (const float*)d_in[2];
  const float* Wdtd  = (const float*)d_in[3];
  const float* bdtd  = (const float*)d_in[4];
  const float* WB    = (const float*)d_in[5];
  const float* WC    = (const float*)d_in[6];
  const float* Dpar  = (const float*)d_in[7];
  const float* Alog  = (const float*)d_in[8];
  const float* diffr = (const float*)d_in[9];
  const int*   Kst   = (const int*)d_in[10];

  // ws layout (13.1 MB): Bmat | Cmat | xT | yT
  float* Bmat = (float*)d_ws;
  float* Cmat = Bmat + (long)MROWS * DST;
  float* xT   = Cmat + (long)MROWS * DST;
  float* yT   = xT + NM;

  // d_out doubles as scratch for the bf16 delta planes between kernels 1 and 2
  unsigned short* dsT = (unsigned short*)d_out;
  unsigned short* ddT = dsT + NM;

  xpose_kernel<<<dim3(NTOK / 32, DIN / 32, BSZ), dim3(256), 0, stream>>>(x, xT);

  proj_kernel<<<dim3(64 * 13), dim3(256), 0, stream>>>(
      x, Wdts, bdts, Wdtd, bdtd, WB, WC, dsT, ddT, Bmat, Cmat);

  ssm_kernel<<<dim3(BSZ * DIN), dim3(512), 0, stream>>>(
      xT, dsT, ddT, Bmat, Cmat, Dpar, Alog, diffr, Kst, yT);

  untranspose_kernel<<<dim3(NTOK / 32, DIN / 32, BSZ), dim3(256), 0, stream>>>(
      yT, (float*)d_out);
}

// Round 10
// 105.494 us; speedup vs baseline: 1.9429x; 1.3518x over previous
//
#include <hip/hip_runtime.h>
#include <hip/hip_bf16.h>

#define BSZ   4
#define NTOK  1024
#define DIN   384
#define DST   16
#define MROWS (BSZ * NTOK)     // 4096
#define NCOLS 800              // 384 dts + 384 dtd + 16 B + 16 C
#define KDIM  384
#define NM    (MROWS * DIN)    // 1572864 elements per plane

__device__ __forceinline__ float softplus_f(float z) {
  return (z > 20.0f) ? z : log1pf(expf(z));
}

__device__ __forceinline__ unsigned short f32_to_bf16(float f) {
  unsigned int u = __float_as_uint(f);
  unsigned int rnd = 0x7fffu + ((u >> 16) & 1u);   // round-to-nearest-even
  return (unsigned short)((u + rnd) >> 16);
}

__device__ __forceinline__ float bf16_lo(unsigned int w) { return __uint_as_float(w << 16); }
__device__ __forceinline__ float bf16_hi(unsigned int w) { return __uint_as_float(w & 0xffff0000u); }

// ---------------------------------------------------------------------------
// Kernel 0: x (b,n,d) -> xT (b,d,n). Both sides coalesced via padded LDS tile.
// ---------------------------------------------------------------------------
__global__ __launch_bounds__(256) void xpose_kernel(
    const float* __restrict__ x, float* __restrict__ xT)
{
  __shared__ float tile[32][33];
  const int n0 = blockIdx.x * 32;
  const int d0 = blockIdx.y * 32;
  const int b  = blockIdx.z;
  const int tx = threadIdx.x & 31, ty = threadIdx.x >> 5;   // ty 0..7
#pragma unroll
  for (int i = 0; i < 4; ++i) {
    int nn = n0 + ty + i * 8;
    tile[ty + i * 8][tx] = x[(long)(b * NTOK + nn) * DIN + d0 + tx];
  }
  __syncthreads();
#pragma unroll
  for (int i = 0; i < 4; ++i) {
    int dd = d0 + ty + i * 8;
    xT[(long)(b * DIN + dd) * NTOK + n0 + tx] = tile[tx][ty + i * 8];
  }
}

// ---------------------------------------------------------------------------
// Kernel 1: fused projection GEMM (4096 x 800 x 384).
//   delta cols -> activated, bf16, written TRANSPOSED (d-major planes in d_out)
//   B/C cols   -> f32 to ws (row-major, small)
// ---------------------------------------------------------------------------
__global__ __launch_bounds__(256) void proj_kernel(
    const float* __restrict__ x,
    const float* __restrict__ Wdts, const float* __restrict__ bdts,
    const float* __restrict__ Wdtd, const float* __restrict__ bdtd,
    const float* __restrict__ WB,   const float* __restrict__ WC,
    unsigned short* __restrict__ dsT, unsigned short* __restrict__ ddT,
    float* __restrict__ Bmat, float* __restrict__ Cmat)
{
  __shared__ float smem[2 * 32 * 68];       // As | Bs (17408 B); reused for epilogue staging
  float* Asp = smem;                        // As[k][m] stride 68
  float* Bsp = smem + 32 * 68;              // Bs[k][c] stride 68

  const int t    = threadIdx.x;
  const int bm   = blockIdx.x & 63;
  const int bn   = blockIdx.x >> 6;
  const int row0 = bm * 64, col0 = bn * 64;
  const int bb   = row0 >> 10;              // batch index (64 | 1024 so tiles never straddle)
  const int n0   = row0 & 1023;
  const int tx = t & 15, ty = t >> 4;
  const int lr = t >> 3;                    // 0..31
  const int lk = (t & 7) * 4;               // 0..28

  float acc[4][4] = {{0.f,0.f,0.f,0.f},{0.f,0.f,0.f,0.f},
                     {0.f,0.f,0.f,0.f},{0.f,0.f,0.f,0.f}};

  for (int k0 = 0; k0 < KDIM; k0 += 32) {
#pragma unroll
    for (int h = 0; h < 2; ++h) {
      int r = lr + h * 32;
      float4 v = *(const float4*)&x[(long)(row0 + r) * KDIM + k0 + lk];
      Asp[(lk+0)*68 + r] = v.x; Asp[(lk+1)*68 + r] = v.y;
      Asp[(lk+2)*68 + r] = v.z; Asp[(lk+3)*68 + r] = v.w;
    }
#pragma unroll
    for (int h = 0; h < 2; ++h) {
      int cc = lr + h * 32;
      int c  = col0 + cc;
      float4 v = make_float4(0.f, 0.f, 0.f, 0.f);
      if (c < NCOLS) {
        const float* wrow;
        if (c < 384)      wrow = Wdts + (long)c * KDIM;
        else if (c < 768) wrow = Wdtd + (long)(c - 384) * KDIM;
        else if (c < 784) wrow = WB   + (long)(c - 768) * KDIM;
        else              wrow = WC   + (long)(c - 784) * KDIM;
        v = *(const float4*)&wrow[k0 + lk];
      }
      Bsp[(lk+0)*68 + cc] = v.x; Bsp[(lk+1)*68 + cc] = v.y;
      Bsp[(lk+2)*68 + cc] = v.z; Bsp[(lk+3)*68 + cc] = v.w;
    }
    __syncthreads();
#pragma unroll
    for (int k = 0; k < 32; ++k) {
      float4 a   = *(const float4*)&Asp[k*68 + ty*4];
      float4 bb4 = *(const float4*)&Bsp[k*68 + tx*4];
      float av[4] = {a.x, a.y, a.z, a.w};
      float bv[4] = {bb4.x, bb4.y, bb4.z, bb4.w};
#pragma unroll
      for (int i = 0; i < 4; ++i)
#pragma unroll
        for (int jj = 0; jj < 4; ++jj)
          acc[i][jj] = fmaf(av[i], bv[jj], acc[i][jj]);
    }
    __syncthreads();
  }

  if (bn < 12) {
    // delta tile: activate, pack bf16, transpose via LDS, write d-major coalesced
    const float* bias = (bn < 6) ? bdts : bdtd;
    unsigned short* plane = (bn < 6) ? dsT : ddT;
    const int cbase = (bn < 6) ? col0 : col0 - 384;   // d index of local col 0
    unsigned int* st32 = (unsigned int*)smem;         // [64 cols][36] u32 (pairs along n)
#pragma unroll
    for (int jj = 0; jj < 4; ++jj) {
      int cl = tx * 4 + jj;
      float b0 = bias[cbase + cl];
      float v0 = fminf(softplus_f(acc[0][jj] + b0), 0.15f);
      float v1 = fminf(softplus_f(acc[1][jj] + b0), 0.15f);
      float v2 = fminf(softplus_f(acc[2][jj] + b0), 0.15f);
      float v3 = fminf(softplus_f(acc[3][jj] + b0), 0.15f);
      unsigned int w0 = (unsigned int)f32_to_bf16(v0) | ((unsigned int)f32_to_bf16(v1) << 16);
      unsigned int w1 = (unsigned int)f32_to_bf16(v2) | ((unsigned int)f32_to_bf16(v3) << 16);
      st32[cl * 36 + ty * 2 + 0] = w0;
      st32[cl * 36 + ty * 2 + 1] = w1;
    }
    __syncthreads();
    {
      int cl = t >> 2, seg = t & 3;
      uint4 w0 = *(const uint4*)&st32[cl * 36 + seg * 8];
      uint4 w1 = *(const uint4*)&st32[cl * 36 + seg * 8 + 4];
      long addr = (long)(bb * DIN + cbase + cl) * NTOK + n0 + seg * 16;
      *(uint4*)&plane[addr]     = w0;   // 8 bf16 values (n .. n+7)
      *(uint4*)&plane[addr + 8] = w1;   // n+8 .. n+15
    }
  } else {
    // B/C tile: direct f32 writes (small)
#pragma unroll
    for (int i = 0; i < 4; ++i) {
      int r = row0 + ty * 4 + i;
#pragma unroll
      for (int jj = 0; jj < 4; ++jj) {
        int c = col0 + tx * 4 + jj;
        float v = acc[i][jj];
        if (c < 784)       Bmat[(long)r * DST + (c - 768)] = v;
        else if (c < 800)  Cmat[(long)r * DST + (c - 784)] = v;
      }
    }
  }
}

// ---------------------------------------------------------------------------
// Kernel 2: per-(b,d) recurrence. 512 threads x 2 rows. h mirrored bf16 in LDS.
// launch_bounds (512,2): do NOT cap VGPRs below the ~110-f32 live state
// (round-9: (512,4) forced VGPR=64 -> 126 MB scratch spill traffic).
// Block-uniform A_s lives in LDS (broadcast reads) to keep VGPR <= 128.
// ---------------------------------------------------------------------------
__global__ __launch_bounds__(512, 2) void ssm_kernel(
    const float* __restrict__ xT,
    const unsigned short* __restrict__ dsT,
    const unsigned short* __restrict__ ddT,
    const float* __restrict__ Bmat, const float* __restrict__ Cmat,
    const float* __restrict__ Dparam, const float* __restrict__ Alog,
    const float* __restrict__ diffraw, const int* __restrict__ Kp,
    float* __restrict__ yT)
{
  __shared__ unsigned int hl[NTOK * 12];    // 49152 B: 8 u32 data + 4 pad per row
  __shared__ float A_sh[16];                // block-uniform -softplus(A_log[d,:])
  const int t = threadIdx.x;
  const int d = blockIdx.x % DIN;
  const int b = blockIdx.x / DIN;
  const int K = Kp[0];
  const float dt = 1.0f / (float)K;
  const float Dc = 0.5f / (1.0f + expf(-diffraw[d]));
  const float Dp = Dparam[d];

  if (t < 16)
    A_sh[t] = -log1pf(expf(Alog[d * DST + t]));

  const long col = (long)(b * DIN + d) * NTOK;

  float hreg[2][16], h0r[2][16], a1[2], a2[2], resid[2];
#pragma unroll
  for (int j = 0; j < 2; ++j) {
    const int n = t + j * 512;
    float xv = xT[col + n];
    resid[j] = xv * Dp;
    float dsv = __uint_as_float((unsigned int)dsT[col + n] << 16);
    float ddv = __uint_as_float((unsigned int)ddT[col + n] << 16);
    a1[j] = dt * dsv;
    a2[j] = dt * ddv * Dc;
    const float4* Bp = (const float4*)&Bmat[(long)(b * NTOK + n) * DST];
#pragma unroll
    for (int q = 0; q < 4; ++q) {
      float4 bv = Bp[q];
      h0r[j][q*4+0] = xv * bv.x; h0r[j][q*4+1] = xv * bv.y;
      h0r[j][q*4+2] = xv * bv.z; h0r[j][q*4+3] = xv * bv.w;
    }
#pragma unroll
    for (int s = 0; s < 16; ++s) hreg[j][s] = h0r[j][s];
    unsigned int pk[8];
#pragma unroll
    for (int q = 0; q < 8; ++q)
      pk[q] = (__float_as_uint(hreg[j][2*q]) >> 16) |
              (__float_as_uint(hreg[j][2*q+1]) & 0xffff0000u);
    *(uint4*)&hl[n * 12]     = make_uint4(pk[0], pk[1], pk[2], pk[3]);
    *(uint4*)&hl[n * 12 + 4] = make_uint4(pk[4], pk[5], pk[6], pk[7]);
  }
  __syncthreads();

  for (int k = 0; k < K; ++k) {
#pragma unroll
    for (int j = 0; j < 2; ++j) {
      const int n = t + j * 512;
      const int r = n >> 5, c = n & 31;
      const int ou  = ((r > 0)  ? n - 32 : n) * 12;
      const int od  = ((r < 31) ? n + 32 : n) * 12;
      const int ol  = ((c > 0)  ? n - 1  : n) * 12;
      const int orr = ((c < 31) ? n + 1  : n) * 12;
#pragma unroll
      for (int hh = 0; hh < 2; ++hh) {
        uint4 qu = *(const uint4*)&hl[ou  + hh * 4];
        uint4 qd = *(const uint4*)&hl[od  + hh * 4];
        uint4 ql = *(const uint4*)&hl[ol  + hh * 4];
        uint4 qr = *(const uint4*)&hl[orr + hh * 4];
        float lap[8];
#pragma unroll
        for (int w = 0; w < 4; ++w) {
          unsigned int uw = (&qu.x)[w], dw = (&qd.x)[w];
          unsigned int lw = (&ql.x)[w], rw = (&qr.x)[w];
          lap[2*w]   = (bf16_lo(uw) + bf16_lo(dw)) + (bf16_lo(lw) + bf16_lo(rw));
          lap[2*w+1] = (bf16_hi(uw) + bf16_hi(dw)) + (bf16_hi(lw) + bf16_hi(rw));
        }
#pragma unroll
        for (int e = 0; e < 8; ++e) {
          const int s = hh * 8 + e;
          float ce = hreg[j][s];
          float lp = lap[e] - 4.0f * ce;
          float t1 = fmaf(A_sh[s], ce, h0r[j][s]);  // A*h + h0 (A_sh: LDS broadcast)
          float hv = fmaf(a1[j], t1, ce);           // h + dt*ds*(...)
          hreg[j][s] = fmaf(a2[j], lp, hv);         // + dt*dd*Dc*lap
        }
      }
    }
    if (k + 1 < K) {
      __syncthreads();
#pragma unroll
      for (int j = 0; j < 2; ++j) {
        const int n = t + j * 512;
        unsigned int pk[8];
#pragma unroll
        for (int q = 0; q < 8; ++q)
          pk[q] = (__float_as_uint(hreg[j][2*q]) >> 16) |
                  (__float_as_uint(hreg[j][2*q+1]) & 0xffff0000u);
        *(uint4*)&hl[n * 12]     = make_uint4(pk[0], pk[1], pk[2], pk[3]);
        *(uint4*)&hl[n * 12 + 4] = make_uint4(pk[4], pk[5], pk[6], pk[7]);
      }
      __syncthreads();
    }
  }

#pragma unroll
  for (int j = 0; j < 2; ++j) {
    const int n = t + j * 512;
    const float4* Cp = (const float4*)&Cmat[(long)(b * NTOK + n) * DST];
    float acc = 0.f;
#pragma unroll
    for (int q = 0; q < 4; ++q) {
      float4 cv = Cp[q];
      acc += hreg[j][q*4+0] * cv.x + hreg[j][q*4+1] * cv.y +
             hreg[j][q*4+2] * cv.z + hreg[j][q*4+3] * cv.w;
    }
    yT[col + n] = acc + resid[j];
  }
}

// ---------------------------------------------------------------------------
// Kernel 3: yT (b,d,n) -> out (b,n,d), both sides coalesced via LDS tile.
// ---------------------------------------------------------------------------
__global__ __launch_bounds__(256) void untranspose_kernel(
    const float* __restrict__ yT, float* __restrict__ out)
{
  __shared__ float tile[32][33];
  const int n0 = blockIdx.x * 32;
  const int d0 = blockIdx.y * 32;
  const int b  = blockIdx.z;
  const int tx = threadIdx.x & 31, ty = threadIdx.x >> 5;   // ty 0..7
#pragma unroll
  for (int i = 0; i < 4; ++i) {
    int dd = d0 + ty + i * 8;
    tile[ty + i * 8][tx] = yT[(long)(b * DIN + dd) * NTOK + n0 + tx];
  }
  __syncthreads();
#pragma unroll
  for (int i = 0; i < 4; ++i) {
    int nn = n0 + ty + i * 8;
    out[(long)(b * NTOK + nn) * DIN + d0 + tx] = tile[tx][ty + i * 8];
  }
}

extern "C" void kernel_launch(void* const* d_in, const int* in_sizes, int n_in,
                              void* d_out, int out_size, void* d_ws, size_t ws_size,
                              hipStream_t stream) {
  const float* x     = (const float*)d_in[0];
  const float* Wdts  = (const float*)d_in[1];
  const float* bdts  = (const float*)d_in[2];
  const float* Wdtd  = (const float*)d_in[3];
  const float* bdtd  = (const float*)d_in[4];
  const float* WB    = (const float*)d_in[5];
  const float* WC    = (const float*)d_in[6];
  const float* Dpar  = (const float*)d_in[7];
  const float* Alog  = (const float*)d_in[8];
  const float* diffr = (const float*)d_in[9];
  const int*   Kst   = (const int*)d_in[10];

  // ws layout (13.1 MB): Bmat | Cmat | xT | yT
  float* Bmat = (float*)d_ws;
  float* Cmat = Bmat + (long)MROWS * DST;
  float* xT   = Cmat + (long)MROWS * DST;
  float* yT   = xT + NM;

  // d_out doubles as scratch for the bf16 delta planes between kernels 1 and 2
  unsigned short* dsT = (unsigned short*)d_out;
  unsigned short* ddT = dsT + NM;

  xpose_kernel<<<dim3(NTOK / 32, DIN / 32, BSZ), dim3(256), 0, stream>>>(x, xT);

  proj_kernel<<<dim3(64 * 13), dim3(256), 0, stream>>>(
      x, Wdts, bdts, Wdtd, bdtd, WB, WC, dsT, ddT, Bmat, Cmat);

  ssm_kernel<<<dim3(BSZ * DIN), dim3(512), 0, stream>>>(
      xT, dsT, ddT, Bmat, Cmat, Dpar, Alog, diffr, Kst, yT);

  untranspose_kernel<<<dim3(NTOK / 32, DIN / 32, BSZ), dim3(256), 0, stream>>>(
      yT, (float*)d_out);
}

// Round 11
// 105.072 us; speedup vs baseline: 1.9507x; 1.0040x over previous
//
#include <hip/hip_runtime.h>
#include <hip/hip_bf16.h>

#define BSZ   4
#define NTOK  1024
#define DIN   384
#define DST   16
#define MROWS (BSZ * NTOK)     // 4096
#define KDIM  384
#define NM    (MROWS * DIN)    // 1572864 elements per plane

typedef __attribute__((ext_vector_type(8))) short bf16x8;
typedef __attribute__((ext_vector_type(4))) float f32x4;

__device__ __forceinline__ float softplus_f(float z) {
  return (z > 20.0f) ? z : log1pf(expf(z));
}

__device__ __forceinline__ unsigned short f32_to_bf16(float f) {
  unsigned int u = __float_as_uint(f);
  unsigned int rnd = 0x7fffu + ((u >> 16) & 1u);   // round-to-nearest-even
  return (unsigned short)((u + rnd) >> 16);
}

__device__ __forceinline__ float bf16_lo(unsigned int w) { return __uint_as_float(w << 16); }
__device__ __forceinline__ float bf16_hi(unsigned int w) { return __uint_as_float(w & 0xffff0000u); }

// ---------------------------------------------------------------------------
// Kernel W: weights (dts|dtd) f32 -> bf16 rows Wb[768][384]
// ---------------------------------------------------------------------------
__global__ __launch_bounds__(256) void wconv_kernel(
    const float* __restrict__ Wdts, const float* __restrict__ Wdtd,
    unsigned short* __restrict__ Wb)
{
  const int idx8 = (blockIdx.x * 256 + threadIdx.x) * 8;   // 144 blocks x 256 x 8 = 294912
  const int row = idx8 / KDIM;
  const int k   = idx8 % KDIM;
  const float* src = (row < 384) ? (Wdts + (long)row * KDIM + k)
                                 : (Wdtd + (long)(row - 384) * KDIM + k);
  float4 v0 = *(const float4*)src;
  float4 v1 = *(const float4*)(src + 4);
  uint4 o;
  o.x = (unsigned int)f32_to_bf16(v0.x) | ((unsigned int)f32_to_bf16(v0.y) << 16);
  o.y = (unsigned int)f32_to_bf16(v0.z) | ((unsigned int)f32_to_bf16(v0.w) << 16);
  o.z = (unsigned int)f32_to_bf16(v1.x) | ((unsigned int)f32_to_bf16(v1.y) << 16);
  o.w = (unsigned int)f32_to_bf16(v1.z) | ((unsigned int)f32_to_bf16(v1.w) << 16);
  *(uint4*)&Wb[idx8] = o;
}

// ---------------------------------------------------------------------------
// Kernel 0: x (b,n,d) -> xT (b,d,n) f32  AND  xb (b,n,d) bf16 (for MFMA).
// ---------------------------------------------------------------------------
__global__ __launch_bounds__(256) void xpose_kernel(
    const float* __restrict__ x, float* __restrict__ xT,
    unsigned short* __restrict__ xb)
{
  __shared__ float tile[32][33];
  const int n0 = blockIdx.x * 32;
  const int d0 = blockIdx.y * 32;
  const int b  = blockIdx.z;
  const int tx = threadIdx.x & 31, ty = threadIdx.x >> 5;   // ty 0..7
#pragma unroll
  for (int i = 0; i < 4; ++i) {
    int nn = n0 + ty + i * 8;
    float v = x[(long)(b * NTOK + nn) * DIN + d0 + tx];
    tile[ty + i * 8][tx] = v;
    xb[(long)(b * NTOK + nn) * DIN + d0 + tx] = f32_to_bf16(v);
  }
  __syncthreads();
#pragma unroll
  for (int i = 0; i < 4; ++i) {
    int dd = d0 + ty + i * 8;
    xT[(long)(b * DIN + dd) * NTOK + n0 + tx] = tile[tx][ty + i * 8];
  }
}

// ---------------------------------------------------------------------------
// Kernel 1a: delta projection GEMM via bf16 MFMA (4096 x 768 x 384).
// 64x64 tile, 4 waves, each wave 32x32 via 2x2 mfma_f32_16x16x32_bf16 frags.
// Epilogue: softplus+clamp, bf16, LDS transpose, d-major coalesced plane write.
// ---------------------------------------------------------------------------
__global__ __launch_bounds__(256) void proj_mfma_kernel(
    const unsigned short* __restrict__ xb,   // bf16 x, row-major [4096][384]
    const unsigned short* __restrict__ Wb,   // bf16 W, row-major [768][384]
    const float* __restrict__ bdts, const float* __restrict__ bdtd,
    unsigned short* __restrict__ dsT, unsigned short* __restrict__ ddT)
{
  __shared__ short smem_s[5120];          // 10240 B: Asm(2560) | Wsm(2560); reused as out_lds
  short* Asm = smem_s;                    // [64 rows][40] bf16 (pad 32->40)
  short* Wsm = smem_s + 2560;             // [64 cols][40] bf16

  const int t    = threadIdx.x;
  const int bm   = blockIdx.x & 63;       // 64 row tiles
  const int bn   = blockIdx.x >> 6;       // 12 col tiles
  const int row0 = bm * 64;
  const int col0 = bn * 64;               // in 0..767
  const int bat  = row0 >> 10;
  const int n0   = row0 & 1023;

  const int l  = t & 63;
  const int w  = t >> 6;
  const int wr = (w >> 1) * 32;           // wave row base in tile
  const int wc = (w & 1) * 32;            // wave col base in tile
  const int lr = l & 15;                  // frag row/col lane index
  const int lk = (l >> 4) * 8;            // frag k offset (bf16)

  const int sr = t >> 2;                  // staging row 0..63
  const int sk = (t & 3) * 8;             // staging k offset

  f32x4 acc[2][2];
  const f32x4 zero = {0.f, 0.f, 0.f, 0.f};
  acc[0][0] = zero; acc[0][1] = zero; acc[1][0] = zero; acc[1][1] = zero;

  for (int k0 = 0; k0 < KDIM; k0 += 32) {
    uint4 av = *(const uint4*)&xb[(long)(row0 + sr) * KDIM + k0 + sk];
    uint4 wv = *(const uint4*)&Wb[(long)(col0 + sr) * KDIM + k0 + sk];
    __syncthreads();                      // prev iter's frag reads done
    *(uint4*)&Asm[sr * 40 + sk] = av;
    *(uint4*)&Wsm[sr * 40 + sk] = wv;
    __syncthreads();
    bf16x8 a0 = *(const bf16x8*)&Asm[(wr + lr) * 40 + lk];
    bf16x8 a1 = *(const bf16x8*)&Asm[(wr + 16 + lr) * 40 + lk];
    bf16x8 b0 = *(const bf16x8*)&Wsm[(wc + lr) * 40 + lk];
    bf16x8 b1 = *(const bf16x8*)&Wsm[(wc + 16 + lr) * 40 + lk];
    acc[0][0] = __builtin_amdgcn_mfma_f32_16x16x32_bf16(a0, b0, acc[0][0], 0, 0, 0);
    acc[0][1] = __builtin_amdgcn_mfma_f32_16x16x32_bf16(a0, b1, acc[0][1], 0, 0, 0);
    acc[1][0] = __builtin_amdgcn_mfma_f32_16x16x32_bf16(a1, b0, acc[1][0], 0, 0, 0);
    acc[1][1] = __builtin_amdgcn_mfma_f32_16x16x32_bf16(a1, b1, acc[1][1], 0, 0, 0);
  }

  // epilogue: activation + bf16 + transpose to [d][n] in LDS
  const float* bias = (bn < 6) ? bdts : bdtd;
  unsigned short* plane = (bn < 6) ? dsT : ddT;
  const int dbase = (bn < 6) ? col0 : col0 - 384;
  const float bv0 = bias[dbase + wc + lr];
  const float bv1 = bias[dbase + wc + 16 + lr];

  __syncthreads();                        // all frag reads done before alias reuse
  unsigned short* outl = (unsigned short*)smem_s;   // [64 d][72 n] u16 (9216 B)
#pragma unroll
  for (int i = 0; i < 2; ++i) {
#pragma unroll
    for (int j = 0; j < 2; ++j) {
      const float bb = j ? bv1 : bv0;
      const int cl = wc + j * 16 + lr;
#pragma unroll
      for (int q = 0; q < 4; ++q) {
        const int nl = wr + i * 16 + (l >> 4) * 4 + q;
        float dl = fminf(softplus_f(acc[i][j][q] + bb), 0.15f);
        outl[cl * 72 + nl] = f32_to_bf16(dl);
      }
    }
  }
  __syncthreads();
  {
    const int dl = t >> 2;                // 0..63
    const int seg = t & 3;                // 16 u16 each
    uint4 w0 = *(const uint4*)&outl[dl * 72 + seg * 16];
    uint4 w1 = *(const uint4*)&outl[dl * 72 + seg * 16 + 8];
    long addr = (long)(bat * DIN + dbase + dl) * NTOK + n0 + seg * 16;
    *(uint4*)&plane[addr]     = w0;
    *(uint4*)&plane[addr + 8] = w1;
  }
}

// ---------------------------------------------------------------------------
// Kernel 1b: B/C projections in f32 (4096 x 32 x 384). Thread-per-element.
// ---------------------------------------------------------------------------
__global__ __launch_bounds__(256) void projBC_kernel(
    const float* __restrict__ x,
    const float* __restrict__ WB, const float* __restrict__ WC,
    float* __restrict__ Bmat, float* __restrict__ Cmat)
{
  const int t  = threadIdx.x;
  const int c  = t & 31;                  // 0-15: B, 16-31: C
  const int rl = t >> 5;                  // 0..7
  const long row = (long)blockIdx.x * 8 + rl;   // 512 blocks
  const float* wrow = (c < 16) ? (WB + (long)c * KDIM) : (WC + (long)(c - 16) * KDIM);
  const float* xrow = x + row * KDIM;
  float acc = 0.f;
#pragma unroll 4
  for (int k = 0; k < KDIM; k += 4) {
    float4 xv = *(const float4*)&xrow[k];
    float4 wv = *(const float4*)&wrow[k];
    acc += xv.x * wv.x + xv.y * wv.y + xv.z * wv.z + xv.w * wv.w;
  }
  if (c < 16) Bmat[row * DST + c] = acc;
  else        Cmat[row * DST + (c - 16)] = acc;
}

// ---------------------------------------------------------------------------
// Kernel 2: per-(b,d) recurrence. 512 threads x 2 rows. h mirrored bf16 in LDS.
// (512,2): do NOT cap VGPRs below the ~110-f32 live state (round-9 spill lesson).
// ---------------------------------------------------------------------------
__global__ __launch_bounds__(512, 2) void ssm_kernel(
    const float* __restrict__ xT,
    const unsigned short* __restrict__ dsT,
    const unsigned short* __restrict__ ddT,
    const float* __restrict__ Bmat, const float* __restrict__ Cmat,
    const float* __restrict__ Dparam, const float* __restrict__ Alog,
    const float* __restrict__ diffraw, const int* __restrict__ Kp,
    float* __restrict__ yT)
{
  __shared__ unsigned int hl[NTOK * 12];    // 49152 B
  __shared__ float A_sh[16];
  const int t = threadIdx.x;
  const int d = blockIdx.x % DIN;
  const int b = blockIdx.x / DIN;
  const int K = Kp[0];
  const float dt = 1.0f / (float)K;
  const float Dc = 0.5f / (1.0f + expf(-diffraw[d]));
  const float Dp = Dparam[d];

  if (t < 16)
    A_sh[t] = -log1pf(expf(Alog[d * DST + t]));

  const long col = (long)(b * DIN + d) * NTOK;

  float hreg[2][16], h0r[2][16], a1[2], a2[2], resid[2];
#pragma unroll
  for (int j = 0; j < 2; ++j) {
    const int n = t + j * 512;
    float xv = xT[col + n];
    resid[j] = xv * Dp;
    float dsv = __uint_as_float((unsigned int)dsT[col + n] << 16);
    float ddv = __uint_as_float((unsigned int)ddT[col + n] << 16);
    a1[j] = dt * dsv;
    a2[j] = dt * ddv * Dc;
    const float4* Bp = (const float4*)&Bmat[(long)(b * NTOK + n) * DST];
#pragma unroll
    for (int q = 0; q < 4; ++q) {
      float4 bv = Bp[q];
      h0r[j][q*4+0] = xv * bv.x; h0r[j][q*4+1] = xv * bv.y;
      h0r[j][q*4+2] = xv * bv.z; h0r[j][q*4+3] = xv * bv.w;
    }
#pragma unroll
    for (int s = 0; s < 16; ++s) hreg[j][s] = h0r[j][s];
    unsigned int pk[8];
#pragma unroll
    for (int q = 0; q < 8; ++q)
      pk[q] = (__float_as_uint(hreg[j][2*q]) >> 16) |
              (__float_as_uint(hreg[j][2*q+1]) & 0xffff0000u);
    *(uint4*)&hl[n * 12]     = make_uint4(pk[0], pk[1], pk[2], pk[3]);
    *(uint4*)&hl[n * 12 + 4] = make_uint4(pk[4], pk[5], pk[6], pk[7]);
  }
  __syncthreads();

  for (int k = 0; k < K; ++k) {
#pragma unroll
    for (int j = 0; j < 2; ++j) {
      const int n = t + j * 512;
      const int r = n >> 5, c = n & 31;
      const int ou  = ((r > 0)  ? n - 32 : n) * 12;
      const int od  = ((r < 31) ? n + 32 : n) * 12;
      const int ol  = ((c > 0)  ? n - 1  : n) * 12;
      const int orr = ((c < 31) ? n + 1  : n) * 12;
#pragma unroll
      for (int hh = 0; hh < 2; ++hh) {
        uint4 qu = *(const uint4*)&hl[ou  + hh * 4];
        uint4 qd = *(const uint4*)&hl[od  + hh * 4];
        uint4 ql = *(const uint4*)&hl[ol  + hh * 4];
        uint4 qr = *(const uint4*)&hl[orr + hh * 4];
        float lap[8];
#pragma unroll
        for (int ww = 0; ww < 4; ++ww) {
          unsigned int uw = (&qu.x)[ww], dw = (&qd.x)[ww];
          unsigned int lw = (&ql.x)[ww], rw = (&qr.x)[ww];
          lap[2*ww]   = (bf16_lo(uw) + bf16_lo(dw)) + (bf16_lo(lw) + bf16_lo(rw));
          lap[2*ww+1] = (bf16_hi(uw) + bf16_hi(dw)) + (bf16_hi(lw) + bf16_hi(rw));
        }
#pragma unroll
        for (int e = 0; e < 8; ++e) {
          const int s = hh * 8 + e;
          float ce = hreg[j][s];
          float lp = lap[e] - 4.0f * ce;
          float t1 = fmaf(A_sh[s], ce, h0r[j][s]);
          float hv = fmaf(a1[j], t1, ce);
          hreg[j][s] = fmaf(a2[j], lp, hv);
        }
      }
    }
    if (k + 1 < K) {
      __syncthreads();
#pragma unroll
      for (int j = 0; j < 2; ++j) {
        const int n = t + j * 512;
        unsigned int pk[8];
#pragma unroll
        for (int q = 0; q < 8; ++q)
          pk[q] = (__float_as_uint(hreg[j][2*q]) >> 16) |
                  (__float_as_uint(hreg[j][2*q+1]) & 0xffff0000u);
        *(uint4*)&hl[n * 12]     = make_uint4(pk[0], pk[1], pk[2], pk[3]);
        *(uint4*)&hl[n * 12 + 4] = make_uint4(pk[4], pk[5], pk[6], pk[7]);
      }
      __syncthreads();
    }
  }

#pragma unroll
  for (int j = 0; j < 2; ++j) {
    const int n = t + j * 512;
    const float4* Cp = (const float4*)&Cmat[(long)(b * NTOK + n) * DST];
    float acc = 0.f;
#pragma unroll
    for (int q = 0; q < 4; ++q) {
      float4 cv = Cp[q];
      acc += hreg[j][q*4+0] * cv.x + hreg[j][q*4+1] * cv.y +
             hreg[j][q*4+2] * cv.z + hreg[j][q*4+3] * cv.w;
    }
    yT[col + n] = acc + resid[j];
  }
}

// ---------------------------------------------------------------------------
// Kernel 3: yT (b,d,n) -> out (b,n,d), both sides coalesced via LDS tile.
// ---------------------------------------------------------------------------
__global__ __launch_bounds__(256) void untranspose_kernel(
    const float* __restrict__ yT, float* __restrict__ out)
{
  __shared__ float tile[32][33];
  const int n0 = blockIdx.x * 32;
  const int d0 = blockIdx.y * 32;
  const int b  = blockIdx.z;
  const int tx = threadIdx.x & 31, ty = threadIdx.x >> 5;
#pragma unroll
  for (int i = 0; i < 4; ++i) {
    int dd = d0 + ty + i * 8;
    tile[ty + i * 8][tx] = yT[(long)(b * DIN + dd) * NTOK + n0 + tx];
  }
  __syncthreads();
#pragma unroll
  for (int i = 0; i < 4; ++i) {
    int nn = n0 + ty + i * 8;
    out[(long)(b * NTOK + nn) * DIN + d0 + tx] = tile[tx][ty + i * 8];
  }
}

extern "C" void kernel_launch(void* const* d_in, const int* in_sizes, int n_in,
                              void* d_out, int out_size, void* d_ws, size_t ws_size,
                              hipStream_t stream) {
  const float* x     = (const float*)d_in[0];
  const float* Wdts  = (const float*)d_in[1];
  const float* bdts  = (const float*)d_in[2];
  const float* Wdtd  = (const float*)d_in[3];
  const float* bdtd  = (const float*)d_in[4];
  const float* WB    = (const float*)d_in[5];
  const float* WC    = (const float*)d_in[6];
  const float* Dpar  = (const float*)d_in[7];
  const float* Alog  = (const float*)d_in[8];
  const float* diffr = (const float*)d_in[9];
  const int*   Kst   = (const int*)d_in[10];

  // ws layout (13.1 MB): Bmat | Cmat | xT | yT.  xb+Wb alias the yT region
  // (dead once ssm starts writing yT — stream-ordered).
  float* Bmat = (float*)d_ws;
  float* Cmat = Bmat + (long)MROWS * DST;
  float* xT   = Cmat + (long)MROWS * DST;
  float* yT   = xT + NM;
  unsigned short* xb = (unsigned short*)yT;        // NM bf16 (3.1 MB)
  unsigned short* Wb = xb + NM;                    // 768*384 bf16 (0.59 MB)

  // d_out scratch: bf16 delta planes between proj and ssm
  unsigned short* dsT = (unsigned short*)d_out;
  unsigned short* ddT = dsT + NM;

  wconv_kernel<<<dim3(144), dim3(256), 0, stream>>>(Wdts, Wdtd, Wb);

  xpose_kernel<<<dim3(NTOK / 32, DIN / 32, BSZ), dim3(256), 0, stream>>>(x, xT, xb);

  proj_mfma_kernel<<<dim3(64 * 12), dim3(256), 0, stream>>>(
      xb, Wb, bdts, bdtd, dsT, ddT);

  projBC_kernel<<<dim3(512), dim3(256), 0, stream>>>(x, WB, WC, Bmat, Cmat);

  ssm_kernel<<<dim3(BSZ * DIN), dim3(512), 0, stream>>>(
      xT, dsT, ddT, Bmat, Cmat, Dpar, Alog, diffr, Kst, yT);

  untranspose_kernel<<<dim3(NTOK / 32, DIN / 32, BSZ), dim3(256), 0, stream>>>(
      yT, (float*)d_out);
}

// Round 12
// 79.256 us; speedup vs baseline: 2.5861x; 1.3257x over previous
//
#include <hip/hip_runtime.h>
#include <hip/hip_bf16.h>

#define BSZ   4
#define NTOK  1024
#define DIN   384
#define DST   16
#define MROWS (BSZ * NTOK)     // 4096
#define KDIM  384
#define NM    (MROWS * DIN)    // 1572864 elements per plane
#define WROWS 832              // 384 dts + 384 dtd + 16 B + 16 C + 32 pad

typedef __attribute__((ext_vector_type(8))) short bf16x8;
typedef __attribute__((ext_vector_type(4))) float f32x4;

__device__ __forceinline__ float softplus_f(float z) {
  return (z > 20.0f) ? z : log1pf(expf(z));
}

__device__ __forceinline__ unsigned short f32_to_bf16(float f) {
  unsigned int u = __float_as_uint(f);
  unsigned int rnd = 0x7fffu + ((u >> 16) & 1u);   // round-to-nearest-even
  return (unsigned short)((u + rnd) >> 16);
}

__device__ __forceinline__ float bf16_lo(unsigned int w) { return __uint_as_float(w << 16); }
__device__ __forceinline__ float bf16_hi(unsigned int w) { return __uint_as_float(w & 0xffff0000u); }

// ---------------------------------------------------------------------------
// Kernel W: concat(Wdts|Wdtd|WB|WC|0) f32 -> bf16 rows Wb[832][384]
// ---------------------------------------------------------------------------
__global__ __launch_bounds__(256) void wconv_kernel(
    const float* __restrict__ Wdts, const float* __restrict__ Wdtd,
    const float* __restrict__ WB,   const float* __restrict__ WC,
    unsigned short* __restrict__ Wb)
{
  const int idx8 = (blockIdx.x * 256 + threadIdx.x) * 8;   // 156 blocks
  const int row = idx8 / KDIM;
  const int k   = idx8 % KDIM;
  uint4 o = make_uint4(0u, 0u, 0u, 0u);
  if (row < 800) {
    const float* src;
    if (row < 384)      src = Wdts + (long)row * KDIM + k;
    else if (row < 768) src = Wdtd + (long)(row - 384) * KDIM + k;
    else if (row < 784) src = WB   + (long)(row - 768) * KDIM + k;
    else                src = WC   + (long)(row - 784) * KDIM + k;
    float4 v0 = *(const float4*)src;
    float4 v1 = *(const float4*)(src + 4);
    o.x = (unsigned int)f32_to_bf16(v0.x) | ((unsigned int)f32_to_bf16(v0.y) << 16);
    o.y = (unsigned int)f32_to_bf16(v0.z) | ((unsigned int)f32_to_bf16(v0.w) << 16);
    o.z = (unsigned int)f32_to_bf16(v1.x) | ((unsigned int)f32_to_bf16(v1.y) << 16);
    o.w = (unsigned int)f32_to_bf16(v1.z) | ((unsigned int)f32_to_bf16(v1.w) << 16);
  }
  *(uint4*)&Wb[idx8] = o;
}

// ---------------------------------------------------------------------------
// Kernel 0: x (b,n,d) -> xT (b,d,n) f32  AND  xb (b,n,d) bf16 (for MFMA).
// ---------------------------------------------------------------------------
__global__ __launch_bounds__(256) void xpose_kernel(
    const float* __restrict__ x, float* __restrict__ xT,
    unsigned short* __restrict__ xb)
{
  __shared__ float tile[32][33];
  const int n0 = blockIdx.x * 32;
  const int d0 = blockIdx.y * 32;
  const int b  = blockIdx.z;
  const int tx = threadIdx.x & 31, ty = threadIdx.x >> 5;   // ty 0..7
#pragma unroll
  for (int i = 0; i < 4; ++i) {
    int nn = n0 + ty + i * 8;
    float v = x[(long)(b * NTOK + nn) * DIN + d0 + tx];
    tile[ty + i * 8][tx] = v;
    xb[(long)(b * NTOK + nn) * DIN + d0 + tx] = f32_to_bf16(v);
  }
  __syncthreads();
#pragma unroll
  for (int i = 0; i < 4; ++i) {
    int dd = d0 + ty + i * 8;
    xT[(long)(b * DIN + dd) * NTOK + n0 + tx] = tile[tx][ty + i * 8];
  }
}

// ---------------------------------------------------------------------------
// Kernel 1: full projection GEMM via bf16 MFMA (4096 x 832 x 384), BK=64,
// double-buffered LDS, ONE barrier per k-iter, loads issued AFTER the barrier
// (vmcnt drains at barriers -> issuing before them serializes; round-11 bug).
//   bn<12 : delta cols -> softplus+clamp, bf16, LDS-transpose, d-major planes
//   bn==12: B/C cols -> f32 from MFMA accumulators direct to Bmat/Cmat
// ---------------------------------------------------------------------------
__global__ __launch_bounds__(256) void proj_mfma_kernel(
    const unsigned short* __restrict__ xb,   // bf16 x, row-major [4096][384]
    const unsigned short* __restrict__ Wb,   // bf16 W, row-major [832][384]
    const float* __restrict__ bdts, const float* __restrict__ bdtd,
    unsigned short* __restrict__ dsT, unsigned short* __restrict__ ddT,
    float* __restrict__ Bmat, float* __restrict__ Cmat)
{
  __shared__ short smem_s[2][2][64 * 72];   // [buf][A|W][64 rows x 72 pad] = 36864 B

  const int t    = threadIdx.x;
  const int bm   = blockIdx.x & 63;         // 64 row tiles
  const int bn   = blockIdx.x >> 6;         // 13 col tiles
  const int row0 = bm * 64;
  const int col0 = bn * 64;                 // 0..831
  const int bat  = row0 >> 10;
  const int n0   = row0 & 1023;

  const int l  = t & 63;
  const int w  = t >> 6;
  const int wr = (w >> 1) * 32;             // wave row base
  const int wc = (w & 1) * 32;              // wave col base
  const int lr = l & 15;
  const int lk = (l >> 4) * 8;              // k offset in frag (bf16)

  const int sr = t >> 2;                    // staging row 0..63
  const int sk = (t & 3) * 16;              // staging k (shorts), 2x uint4

  f32x4 acc[2][2];
  const f32x4 zero = {0.f, 0.f, 0.f, 0.f};
  acc[0][0] = zero; acc[0][1] = zero; acc[1][0] = zero; acc[1][1] = zero;

  uint4 la0, la1, lw0, lw1;
#define PLOAD(K0)                                                          \
  {                                                                        \
    const unsigned short* ap = &xb[(long)(row0 + sr) * KDIM + (K0) + sk];  \
    const unsigned short* wp = &Wb[(long)(col0 + sr) * KDIM + (K0) + sk];  \
    la0 = *(const uint4*)ap;  la1 = *(const uint4*)(ap + 8);               \
    lw0 = *(const uint4*)wp;  lw1 = *(const uint4*)(wp + 8);               \
  }
#define PSTORE(BUF)                                                        \
  {                                                                        \
    *(uint4*)&smem_s[BUF][0][sr * 72 + sk]     = la0;                      \
    *(uint4*)&smem_s[BUF][0][sr * 72 + sk + 8] = la1;                      \
    *(uint4*)&smem_s[BUF][1][sr * 72 + sk]     = lw0;                      \
    *(uint4*)&smem_s[BUF][1][sr * 72 + sk + 8] = lw1;                      \
  }

  PLOAD(0);
  PSTORE(0);

  for (int it = 0; it < 6; ++it) {
    const int cur = it & 1;
    __syncthreads();                        // lds[cur] writes visible; lds[cur^1] readers done
    if (it + 1 < 6) PLOAD((it + 1) * 64);   // in flight across MFMA + ds_write below
    const short* Asm = smem_s[cur][0];
    const short* Wsm = smem_s[cur][1];
#pragma unroll
    for (int kh = 0; kh < 2; ++kh) {
      const int ko = kh * 32 + lk;
      bf16x8 a0 = *(const bf16x8*)&Asm[(wr + lr) * 72 + ko];
      bf16x8 a1 = *(const bf16x8*)&Asm[(wr + 16 + lr) * 72 + ko];
      bf16x8 b0 = *(const bf16x8*)&Wsm[(wc + lr) * 72 + ko];
      bf16x8 b1 = *(const bf16x8*)&Wsm[(wc + 16 + lr) * 72 + ko];
      acc[0][0] = __builtin_amdgcn_mfma_f32_16x16x32_bf16(a0, b0, acc[0][0], 0, 0, 0);
      acc[0][1] = __builtin_amdgcn_mfma_f32_16x16x32_bf16(a0, b1, acc[0][1], 0, 0, 0);
      acc[1][0] = __builtin_amdgcn_mfma_f32_16x16x32_bf16(a1, b0, acc[1][0], 0, 0, 0);
      acc[1][1] = __builtin_amdgcn_mfma_f32_16x16x32_bf16(a1, b1, acc[1][1], 0, 0, 0);
    }
    if (it + 1 < 6) PSTORE(cur ^ 1);        // vmcnt wait lands here, after MFMA
  }

  if (bn < 12) {
    // delta epilogue: activation, bf16, transpose via LDS, d-major plane write
    const float* bias = (bn < 6) ? bdts : bdtd;
    unsigned short* plane = (bn < 6) ? dsT : ddT;
    const int dbase = (bn < 6) ? col0 : col0 - 384;
    const float bv0 = bias[dbase + wc + lr];
    const float bv1 = bias[dbase + wc + 16 + lr];
    __syncthreads();                        // frag reads done before smem reuse
    unsigned short* outl = (unsigned short*)smem_s;   // [64 d][72 n] u16
#pragma unroll
    for (int i = 0; i < 2; ++i)
#pragma unroll
      for (int j = 0; j < 2; ++j) {
        const float bb = j ? bv1 : bv0;
        const int cl = wc + j * 16 + lr;
#pragma unroll
        for (int q = 0; q < 4; ++q) {
          const int nl = wr + i * 16 + (l >> 4) * 4 + q;
          float dl = fminf(softplus_f(acc[i][j][q] + bb), 0.15f);
          outl[cl * 72 + nl] = f32_to_bf16(dl);
        }
      }
    __syncthreads();
    const int dl = t >> 2;
    const int seg = t & 3;
    uint4 w0 = *(const uint4*)&outl[dl * 72 + seg * 16];
    uint4 w1 = *(const uint4*)&outl[dl * 72 + seg * 16 + 8];
    long addr = (long)(bat * DIN + dbase + dl) * NTOK + n0 + seg * 16;
    *(uint4*)&plane[addr]     = w0;
    *(uint4*)&plane[addr + 8] = w1;
  } else {
    // B/C epilogue: f32 straight from accumulators (cols 0..15 B, 16..31 C)
#pragma unroll
    for (int i = 0; i < 2; ++i)
#pragma unroll
      for (int j = 0; j < 2; ++j) {
        const int cl = wc + j * 16 + lr;
#pragma unroll
        for (int q = 0; q < 4; ++q) {
          const int row = row0 + wr + i * 16 + (l >> 4) * 4 + q;
          if (cl < 16)       Bmat[(long)row * DST + cl] = acc[i][j][q];
          else if (cl < 32)  Cmat[(long)row * DST + (cl - 16)] = acc[i][j][q];
        }
      }
  }
#undef PLOAD
#undef PSTORE
}

// ---------------------------------------------------------------------------
// Kernel 2: per-(b,d) recurrence. 512 threads x 2 rows. h bf16 in LDS, 32 KB:
// 8 u32/row with half-XOR swizzle  phys = n*8 + ((hh ^ ((n>>2)&1))<<2)
// -> lanes cover all 32 banks (2-way over 16 lanes = free), 4 blocks/CU.
// (512,2): don't cap VGPRs below live state (round-9 spill lesson).
// ---------------------------------------------------------------------------
#define HOFF(n, hh) (((n) << 3) + ((((hh) ^ (((n) >> 2) & 1))) << 2))

__global__ __launch_bounds__(512, 2) void ssm_kernel(
    const float* __restrict__ xT,
    const unsigned short* __restrict__ dsT,
    const unsigned short* __restrict__ ddT,
    const float* __restrict__ Bmat, const float* __restrict__ Cmat,
    const float* __restrict__ Dparam, const float* __restrict__ Alog,
    const float* __restrict__ diffraw, const int* __restrict__ Kp,
    float* __restrict__ yT)
{
  __shared__ unsigned int hl[NTOK * 8];     // 32768 B
  __shared__ float A_sh[16];
  const int t = threadIdx.x;
  const int d = blockIdx.x % DIN;
  const int b = blockIdx.x / DIN;
  const int K = Kp[0];
  const float dt = 1.0f / (float)K;
  const float Dc = 0.5f / (1.0f + expf(-diffraw[d]));
  const float Dp = Dparam[d];

  if (t < 16)
    A_sh[t] = -log1pf(expf(Alog[d * DST + t]));

  const long col = (long)(b * DIN + d) * NTOK;

  float hreg[2][16], h0r[2][16], a1[2], a2[2], resid[2];
#pragma unroll
  for (int j = 0; j < 2; ++j) {
    const int n = t + j * 512;
    float xv = xT[col + n];
    resid[j] = xv * Dp;
    float dsv = __uint_as_float((unsigned int)dsT[col + n] << 16);
    float ddv = __uint_as_float((unsigned int)ddT[col + n] << 16);
    a1[j] = dt * dsv;
    a2[j] = dt * ddv * Dc;
    const float4* Bp = (const float4*)&Bmat[(long)(b * NTOK + n) * DST];
#pragma unroll
    for (int q = 0; q < 4; ++q) {
      float4 bv = Bp[q];
      h0r[j][q*4+0] = xv * bv.x; h0r[j][q*4+1] = xv * bv.y;
      h0r[j][q*4+2] = xv * bv.z; h0r[j][q*4+3] = xv * bv.w;
    }
#pragma unroll
    for (int s = 0; s < 16; ++s) hreg[j][s] = h0r[j][s];
    unsigned int pk[8];
#pragma unroll
    for (int q = 0; q < 8; ++q)
      pk[q] = (__float_as_uint(hreg[j][2*q]) >> 16) |
              (__float_as_uint(hreg[j][2*q+1]) & 0xffff0000u);
    *(uint4*)&hl[HOFF(n, 0)] = make_uint4(pk[0], pk[1], pk[2], pk[3]);
    *(uint4*)&hl[HOFF(n, 1)] = make_uint4(pk[4], pk[5], pk[6], pk[7]);
  }
  __syncthreads();

  for (int k = 0; k < K; ++k) {
#pragma unroll
    for (int j = 0; j < 2; ++j) {
      const int n = t + j * 512;
      const int r = n >> 5, c = n & 31;
      const int nu  = (r > 0)  ? n - 32 : n;
      const int nd  = (r < 31) ? n + 32 : n;
      const int nl  = (c > 0)  ? n - 1  : n;
      const int nr  = (c < 31) ? n + 1  : n;
#pragma unroll
      for (int hh = 0; hh < 2; ++hh) {
        uint4 qu = *(const uint4*)&hl[HOFF(nu, hh)];
        uint4 qd = *(const uint4*)&hl[HOFF(nd, hh)];
        uint4 ql = *(const uint4*)&hl[HOFF(nl, hh)];
        uint4 qr = *(const uint4*)&hl[HOFF(nr, hh)];
        float lap[8];
#pragma unroll
        for (int ww = 0; ww < 4; ++ww) {
          unsigned int uw = (&qu.x)[ww], dw = (&qd.x)[ww];
          unsigned int lw = (&ql.x)[ww], rw = (&qr.x)[ww];
          lap[2*ww]   = (bf16_lo(uw) + bf16_lo(dw)) + (bf16_lo(lw) + bf16_lo(rw));
          lap[2*ww+1] = (bf16_hi(uw) + bf16_hi(dw)) + (bf16_hi(lw) + bf16_hi(rw));
        }
#pragma unroll
        for (int e = 0; e < 8; ++e) {
          const int s = hh * 8 + e;
          float ce = hreg[j][s];
          float lp = lap[e] - 4.0f * ce;
          float t1 = fmaf(A_sh[s], ce, h0r[j][s]);
          float hv = fmaf(a1[j], t1, ce);
          hreg[j][s] = fmaf(a2[j], lp, hv);
        }
      }
    }
    if (k + 1 < K) {
      __syncthreads();
#pragma unroll
      for (int j = 0; j < 2; ++j) {
        const int n = t + j * 512;
        unsigned int pk[8];
#pragma unroll
        for (int q = 0; q < 8; ++q)
          pk[q] = (__float_as_uint(hreg[j][2*q]) >> 16) |
                  (__float_as_uint(hreg[j][2*q+1]) & 0xffff0000u);
        *(uint4*)&hl[HOFF(n, 0)] = make_uint4(pk[0], pk[1], pk[2], pk[3]);
        *(uint4*)&hl[HOFF(n, 1)] = make_uint4(pk[4], pk[5], pk[6], pk[7]);
      }
      __syncthreads();
    }
  }

#pragma unroll
  for (int j = 0; j < 2; ++j) {
    const int n = t + j * 512;
    const float4* Cp = (const float4*)&Cmat[(long)(b * NTOK + n) * DST];
    float acc = 0.f;
#pragma unroll
    for (int q = 0; q < 4; ++q) {
      float4 cv = Cp[q];
      acc += hreg[j][q*4+0] * cv.x + hreg[j][q*4+1] * cv.y +
             hreg[j][q*4+2] * cv.z + hreg[j][q*4+3] * cv.w;
    }
    yT[col + n] = acc + resid[j];
  }
}

// ---------------------------------------------------------------------------
// Kernel 3: yT (b,d,n) -> out (b,n,d), both sides coalesced via LDS tile.
// ---------------------------------------------------------------------------
__global__ __launch_bounds__(256) void untranspose_kernel(
    const float* __restrict__ yT, float* __restrict__ out)
{
  __shared__ float tile[32][33];
  const int n0 = blockIdx.x * 32;
  const int d0 = blockIdx.y * 32;
  const int b  = blockIdx.z;
  const int tx = threadIdx.x & 31, ty = threadIdx.x >> 5;
#pragma unroll
  for (int i = 0; i < 4; ++i) {
    int dd = d0 + ty + i * 8;
    tile[ty + i * 8][tx] = yT[(long)(b * DIN + dd) * NTOK + n0 + tx];
  }
  __syncthreads();
#pragma unroll
  for (int i = 0; i < 4; ++i) {
    int nn = n0 + ty + i * 8;
    out[(long)(b * NTOK + nn) * DIN + d0 + tx] = tile[tx][ty + i * 8];
  }
}

extern "C" void kernel_launch(void* const* d_in, const int* in_sizes, int n_in,
                              void* d_out, int out_size, void* d_ws, size_t ws_size,
                              hipStream_t stream) {
  const float* x     = (const float*)d_in[0];
  const float* Wdts  = (const float*)d_in[1];
  const float* bdts  = (const float*)d_in[2];
  const float* Wdtd  = (const float*)d_in[3];
  const float* bdtd  = (const float*)d_in[4];
  const float* WB    = (const float*)d_in[5];
  const float* WC    = (const float*)d_in[6];
  const float* Dpar  = (const float*)d_in[7];
  const float* Alog  = (const float*)d_in[8];
  const float* diffr = (const float*)d_in[9];
  const int*   Kst   = (const int*)d_in[10];

  // ws layout (13.1 MB): Bmat | Cmat | xT | yT.  xb+Wb alias the yT region
  // (dead until ssm writes yT — stream-ordered).
  float* Bmat = (float*)d_ws;
  float* Cmat = Bmat + (long)MROWS * DST;
  float* xT   = Cmat + (long)MROWS * DST;
  float* yT   = xT + NM;
  unsigned short* xb = (unsigned short*)yT;        // NM bf16 (3.1 MB)
  unsigned short* Wb = xb + NM;                    // 832*384 bf16 (0.64 MB)

  // d_out scratch: bf16 delta planes between proj and ssm
  unsigned short* dsT = (unsigned short*)d_out;
  unsigned short* ddT = dsT + NM;

  wconv_kernel<<<dim3(156), dim3(256), 0, stream>>>(Wdts, Wdtd, WB, WC, Wb);

  xpose_kernel<<<dim3(NTOK / 32, DIN / 32, BSZ), dim3(256), 0, stream>>>(x, xT, xb);

  proj_mfma_kernel<<<dim3(64 * 13), dim3(256), 0, stream>>>(
      xb, Wb, bdts, bdtd, dsT, ddT, Bmat, Cmat);

  ssm_kernel<<<dim3(BSZ * DIN), dim3(512), 0, stream>>>(
      xT, dsT, ddT, Bmat, Cmat, Dpar, Alog, diffr, Kst, yT);

  untranspose_kernel<<<dim3(NTOK / 32, DIN / 32, BSZ), dim3(256), 0, stream>>>(
      yT, (float*)d_out);
}